// Round 1
// baseline (212.766 us; speedup 1.0000x reference)
//
#include <hip/hip_runtime.h>
#include <math.h>

#define B_ 16
#define SEQ_ 8192
#define C_ 192
#define H_ 16
#define OV_ 4
#define G_ 6
#define K_ 1024
#define D_ 8
#define DG_ 2048
#define W_ 512
#define T_ 128
#define TT 4
#define OUT_ELEMS (B_ * SEQ_ * C_)   // 25165824

// workspace layout:
//   pd_perm : float [G*DG*D]  = 98304 floats   @ byte 0
//   pu_perm : float [G*D*DG]  = 98304 floats   @ byte 393216
//   cbn_d   : double[G*K*D]   = 49152 doubles  @ byte 786432
// total = 1179648 bytes

// d' = h*128 + ul  <->  group-local d = ul*16 + h,  u = g*128 + ul = o*192 + c

__global__ __launch_bounds__(256) void vq_prep(
    const float* __restrict__ pd, const float* __restrict__ pu,
    const float* __restrict__ cb,
    float* __restrict__ pd_p, float* __restrict__ pu_p,
    double* __restrict__ cbn, float* __restrict__ loss_slots)
{
  int i = blockIdx.x * 256 + threadIdx.x;
  if (i < 98304) {                       // pd_perm[g][d'][e]
    int e = i & 7, dp = (i >> 3) & 2047, g = i >> 14;
    int h = dp >> 7, ul = dp & 127, d = (ul << 4) + h;
    pd_p[i] = pd[(g << 14) + (d << 3) + e];
  } else if (i < 196608) {               // pu_perm[g][e][d']
    int i2 = i - 98304;
    int dp = i2 & 2047, e = (i2 >> 11) & 7, g = i2 >> 14;
    int h = dp >> 7, ul = dp & 127, d = (ul << 4) + h;
    pu_p[i2] = pu[(g << 14) + (e << 11) + d];
  } else if (i < 202752) {               // normalized codebooks, fp64
    int j = i - 196608;                  // j = g*1024 + k
    const float* row = cb + (j << 3);
    double ss = 0.0;
    #pragma unroll
    for (int e = 0; e < 8; ++e) { double x = (double)row[e]; ss += x * x; }
    double inv = 1.0 / fmax(sqrt(ss), 1e-12);
    #pragma unroll
    for (int e = 0; e < 8; ++e) cbn[(j << 3) + e] = (double)row[e] * inv;
  } else if (i < 202784) {               // zero the 32 loss accumulators
    loss_slots[i - 202752] = 0.0f;
  }
}

__global__ __launch_bounds__(256) void vq_main(
    const float* __restrict__ z, const float* __restrict__ cb,
    const float* __restrict__ pd_p, const float* __restrict__ pu_p,
    const double* __restrict__ cbn,
    float* __restrict__ out, float* __restrict__ loss_slots)
{
  __shared__ __align__(16) float zs[TT * DG_];   // 32 KB, aliased as double[4096] later
  __shared__ double ze_d[TT * 8];
  __shared__ float  zq_s[TT * 8];
  __shared__ double wr_s[4][TT];
  __shared__ int    wr_k[4][TT];
  __shared__ float  lossv[TT];

  const int tid = threadIdx.x;
  const int tc  = blockIdx.x;   // 0..31 (chunk of TT=4 grouped frames)
  const int g   = blockIdx.y;   // 0..5
  const int b   = blockIdx.z;   // 0..15

  const float* zb = z + (size_t)b * (SEQ_ * C_);

  // ---------- phase 0: gather z slices -> LDS (float4, coalesced runs) ----------
  #pragma unroll
  for (int t = 0; t < TT; ++t) {
    int wbase = (tc * TT + t) * OV_;
    #pragma unroll
    for (int j = 0; j < 2; ++j) {
      int v  = j * 256 + tid;          // 0..511 float4 slots
      int h  = v >> 5;                 // 32 float4 per h-row
      int ul = (v & 31) << 2;
      int u  = (g << 7) + ul;
      int o  = (u * 683) >> 17;        // u/192 for u<768
      int c  = u - o * 192;
      const float4 val = *(const float4*)(zb + (h * 512 + wbase + o) * 192 + c);
      *(float4*)(&zs[t * DG_ + (h << 7) + ul]) = val;
    }
  }
  __syncthreads();

  // ---------- phase 1: z_e partials (fp64 accum; pd read once per block) ----------
  double acc[TT][8];
  #pragma unroll
  for (int t = 0; t < TT; ++t)
    #pragma unroll
    for (int e = 0; e < 8; ++e) acc[t][e] = 0.0;

  #pragma unroll
  for (int i = 0; i < 8; ++i) {
    int dp = i * 256 + tid;
    const float4 p0 = *(const float4*)(pd_p + ((((g << 11) + dp) << 3)));
    const float4 p1 = *(const float4*)(pd_p + ((((g << 11) + dp) << 3) + 4));
    #pragma unroll
    for (int t = 0; t < TT; ++t) {
      double zv = (double)zs[t * DG_ + dp];
      acc[t][0] = fma(zv, (double)p0.x, acc[t][0]);
      acc[t][1] = fma(zv, (double)p0.y, acc[t][1]);
      acc[t][2] = fma(zv, (double)p0.z, acc[t][2]);
      acc[t][3] = fma(zv, (double)p0.w, acc[t][3]);
      acc[t][4] = fma(zv, (double)p1.x, acc[t][4]);
      acc[t][5] = fma(zv, (double)p1.y, acc[t][5]);
      acc[t][6] = fma(zv, (double)p1.z, acc[t][6]);
      acc[t][7] = fma(zv, (double)p1.w, acc[t][7]);
    }
  }

  // ---------- phase 1.5: block reduction of 32 (t,e) sums, fp64, LDS aliased ----------
  double* part_d = (double*)zs;   // 4096 doubles = 32 KB; 16 kk-slots x 256 partials/round
  #pragma unroll
  for (int r = 0; r < 2; ++r) {
    __syncthreads();   // prior reads of this region are done
    #pragma unroll
    for (int kkl = 0; kkl < 16; ++kkl) {
      int kk = r * 16 + kkl;
      part_d[kkl * 256 + tid] = acc[kk >> 3][kk & 7];
    }
    __syncthreads();
    int kkl = tid >> 4, jj = tid & 15;
    double partial = 0.0;
    #pragma unroll
    for (int s = 0; s < 16; ++s) {
      int p = (s + tid) & 15;          // rotate to spread banks
      partial += part_d[kkl * 256 + jj * 16 + p];
    }
    partial += __shfl_down(partial, 8);
    partial += __shfl_down(partial, 4);
    partial += __shfl_down(partial, 2);
    partial += __shfl_down(partial, 1);
    if (jj == 0) ze_d[r * 16 + kkl] = partial;   // kk = t*8+e
  }
  __syncthreads();

  // ---------- phase 2: argmax over 1024 codes (fp64 sim, first-max tie-break) ----------
  double cd[4][8];
  #pragma unroll
  for (int q = 0; q < 4; ++q) {
    const double* cr = cbn + (((g << 10) + (q << 8) + tid) << 3);
    #pragma unroll
    for (int e = 0; e < 8; ++e) cd[q][e] = cr[e];
  }
  double bs[TT]; int bk[TT];
  #pragma unroll
  for (int t = 0; t < TT; ++t) {
    double zr[8];
    #pragma unroll
    for (int e = 0; e < 8; ++e) zr[e] = ze_d[t * 8 + e];
    bs[t] = -1.0e300; bk[t] = 0x7fffffff;
    #pragma unroll
    for (int q = 0; q < 4; ++q) {
      double s = 0.0;
      #pragma unroll
      for (int e = 0; e < 8; ++e) s = fma(zr[e], cd[q][e], s);
      int k = (q << 8) + tid;          // ascending within thread -> strict > keeps min k
      if (s > bs[t]) { bs[t] = s; bk[t] = k; }
    }
  }
  #pragma unroll
  for (int m = 32; m >= 1; m >>= 1) {
    #pragma unroll
    for (int t = 0; t < TT; ++t) {
      double os = __shfl_xor(bs[t], m);
      int    ok = __shfl_xor(bk[t], m);
      if (os > bs[t] || (os == bs[t] && ok < bk[t])) { bs[t] = os; bk[t] = ok; }
    }
  }
  int wv = tid >> 6;
  if ((tid & 63) == 0) {
    #pragma unroll
    for (int t = 0; t < TT; ++t) { wr_s[wv][t] = bs[t]; wr_k[wv][t] = bk[t]; }
  }
  __syncthreads();
  if (tid < TT) {
    int t = tid;
    double s0 = wr_s[0][t]; int k0 = wr_k[0][t];
    #pragma unroll
    for (int w2 = 1; w2 < 4; ++w2) {
      double s1 = wr_s[w2][t]; int k1 = wr_k[w2][t];
      if (s1 > s0 || (s1 == s0 && k1 < k0)) { s0 = s1; k0 = k1; }
    }
    const float* crow = cb + (((g << 10) + k0) << 3);   // RAW codebook row
    double l = 0.0;
    #pragma unroll
    for (int e = 0; e < 8; ++e) {
      float qv = crow[e];
      zq_s[t * 8 + e] = qv;
      double dd = ze_d[t * 8 + e] - (double)qv;
      l = fma(dd, dd, l);
    }
    lossv[t] = (float)l;
  }
  __syncthreads();
  if (tid == 0) {
    float l = (lossv[0] + lossv[1] + lossv[2] + lossv[3]) * (1.0f / (T_ * D_ * G_));
    atomicAdd(loss_slots + b, l);        // commitment
    atomicAdd(loss_slots + 16 + b, l);   // codebook loss (numerically identical)
  }

  // ---------- phase 3: out = z_q @ proj_up, scatter-coalesced ----------
  float zqr[TT][8];
  #pragma unroll
  for (int t = 0; t < TT; ++t)
    #pragma unroll
    for (int e = 0; e < 8; ++e) zqr[t][e] = zq_s[t * 8 + e];

  #pragma unroll
  for (int j = 0; j < 8; ++j) {
    int dp = j * 256 + tid;
    int h = dp >> 7, ul = dp & 127;
    int u = (g << 7) + ul;
    int o = (u * 683) >> 17;
    int c = u - o * 192;
    float pv[8];
    #pragma unroll
    for (int e = 0; e < 8; ++e) pv[e] = pu_p[(g << 14) + (e << 11) + dp];
    size_t base = ((size_t)(b * SEQ_) + h * 512 + tc * (TT * OV_) + o) * 192 + c;
    #pragma unroll
    for (int t = 0; t < TT; ++t) {
      float v = 0.f;
      #pragma unroll
      for (int e = 0; e < 8; ++e) v = fmaf(zqr[t][e], pv[e], v);
      out[base + (size_t)(t * OV_ * 192)] = v;
    }
  }
}

extern "C" void kernel_launch(void* const* d_in, const int* in_sizes, int n_in,
                              void* d_out, int out_size, void* d_ws, size_t ws_size,
                              hipStream_t stream)
{
  const float* z  = (const float*)d_in[0];   // (B, SEQ, C)
  const float* pd = (const float*)d_in[1];   // (G, DG, D)
  const float* pu = (const float*)d_in[2];   // (G, D, DG)
  const float* cb = (const float*)d_in[3];   // (G, K, D)
  float* out = (float*)d_out;
  float* loss_slots = out + OUT_ELEMS;       // 16 commitment + 16 codebook

  float*  pd_p = (float*)d_ws;
  float*  pu_p = pd_p + 98304;
  double* cbn  = (double*)(pu_p + 98304);

  vq_prep<<<793, 256, 0, stream>>>(pd, pu, cb, pd_p, pu_p, cbn, loss_slots);
  dim3 grid(T_ / TT, G_, B_);
  vq_main<<<grid, 256, 0, stream>>>(z, cb, pd_p, pu_p, cbn, out, loss_slots);
}